// Round 7
// baseline (1040.826 us; speedup 1.0000x reference)
//
#include <hip/hip_runtime.h>
#include <hip/hip_bf16.h>

#define DD 128

typedef __attribute__((ext_vector_type(8))) short short8;
typedef __attribute__((ext_vector_type(8))) unsigned short u16x8;
typedef __attribute__((ext_vector_type(4))) float f32x4;

__device__ __forceinline__ unsigned short f2bf(float f) {
    union { unsigned int u; float f; } c; c.f = f;
    unsigned int u = c.u;
    unsigned int r = (u + 0x7FFFu + ((u >> 16) & 1u)) >> 16;
    return (unsigned short)r;
}
__device__ __forceinline__ float bf2f(unsigned short h) {
    union { unsigned int u; float f; } c; c.u = ((unsigned int)h) << 16; return c.f;
}

// -------- scatter: pre[dst] += bf16(feats[src]) via pk_add_bf16, deg[dst] += 1 --------
__global__ void scatter_kernel(const float* __restrict__ feats,
                               const int* __restrict__ src,
                               const int* __restrict__ dst,
                               const float* __restrict__ u,
                               unsigned int* __restrict__ pre,   // bf16x2 words, 64 per row
                               float* __restrict__ deg,
                               int E)
{
    int gtid = blockIdx.x * blockDim.x + threadIdx.x;
    int lane = gtid & 63;
    int wave = gtid >> 6;
    int nw   = (gridDim.x * blockDim.x) >> 6;
    for (int e = wave; e < E; e += nw) {
        if (u[e] < 0.5f) {
            int s = src[e], d = dst[e];
            float2 x = *(const float2*)(feats + (size_t)s * DD + 2 * lane);
            unsigned int* p = pre + (size_t)d * 64 + lane;
#if defined(__HIP_DEVICE_COMPILE__)
            typedef short sv2 __attribute__((ext_vector_type(2)));
            sv2 v; v[0] = (short)f2bf(x.x); v[1] = (short)f2bf(x.y);
            __builtin_amdgcn_global_atomic_fadd_v2bf16((__attribute__((address_space(1))) sv2*)p, v);
#else
            (void)p; (void)x;
#endif
            if (lane == 0) unsafeAtomicAdd(deg + d, 1.0f);
        }
    }
}

// -------- barrier-free table update, single-pass HBM --------
// comb = X@Wself^T + bself + fmask*((pre/deg)@Wedge^T + (deg>0)*bedge)
// LN -> +residual -> SELU -> column-mask select
// W in LDS (bf16, XOR-swizzled); per-wave 16x128 f32 X-tile staged in LDS.
// Output tile is staged back into the same LDS buffer (in-place over the
// residual) and written with fully-coalesced f32x4 NT stores (full lines,
// no partial-line RMW at HBM).
__global__ __launch_bounds__(512)
void table_kernel(const float* __restrict__ feats,
                  const unsigned short* __restrict__ pre,   // bf16
                  const float* __restrict__ deg,
                  const float* __restrict__ Wself,
                  const float* __restrict__ bself,
                  const float* __restrict__ Wedge,
                  const float* __restrict__ bedge,
                  const float* __restrict__ lnw,
                  const float* __restrict__ lnb,
                  const float* __restrict__ ufeat,
                  float* __restrict__ out,
                  int N)
{
    __shared__ __align__(16) unsigned short wlds[2 * 16384];  // 64KB weights (bf16, swizzled)
    __shared__ f32x4 xstage4[8 * 512];                        // 64KB: 8 waves x 16x128 f32

    const int tid = threadIdx.x;

    // ---- one-time weight staging: f32 -> bf16, XOR-swizzled (addr ^= (j&7)<<4) ----
    {
        int j  = tid >> 2;        // W row (output col) 0..127
        int kq = tid & 3;         // k quarter
        float fm = ufeat[j] < 0.3f ? 1.0f : 0.0f;
        const float* wsrow = Wself + j * DD + kq * 32;
        const float* werow = Wedge + j * DD + kq * 32;
        char* lbs = (char*)wlds;
        #pragma unroll
        for (int c = 0; c < 4; ++c) {
            unsigned short tS[8], tE[8];
            #pragma unroll
            for (int i = 0; i < 8; ++i) {
                tS[i] = f2bf(wsrow[c * 8 + i]);
                tE[i] = f2bf(werow[c * 8 + i] * fm);
            }
            int addr = (j * 256 + kq * 64 + c * 16) ^ ((j & 7) << 4);
            *(short8*)(lbs + addr)         = *(short8*)tS;
            *(short8*)(lbs + 32768 + addr) = *(short8*)tE;
        }
    }
    __syncthreads();   // only barrier in the kernel

    const int wave = tid >> 6;
    const int lane = tid & 63;
    const int lj = lane & 15;
    const int lk = lane >> 4;

    // per-lane column constants (col = ct*16 + lj)
    float bs[8], bem[8], lw[8], lb[8];
    unsigned fmask = 0;
    #pragma unroll
    for (int ct = 0; ct < 8; ++ct) {
        int col = ct * 16 + lj;
        bool fm = ufeat[col] < 0.3f;
        bs[ct]  = bself[col];
        bem[ct] = fm ? bedge[col] : 0.0f;
        lw[ct]  = lnw[col];
        lb[ct]  = lnb[col];
        fmask |= (fm ? 1u : 0u) << ct;
    }

    char* xs = (char*)xstage4 + wave * 8192;
    const char* wb = (const char*)wlds;
    const int ldb  = lj * 256 + lk * 16;
    const int xorv = (lj & 7) << 4;

    const int ntiles = N >> 4;
    for (int tile = blockIdx.x * 8 + wave; tile < ntiles; tile += gridDim.x * 8) {
        int row0 = tile << 4;

        // ---- stage 16x128 f32 X-tile to LDS (coalesced NT loads, swizzled writes) ----
        #pragma unroll
        for (int j = 0; j < 8; ++j) {
            int fidx = j * 64 + lane;
            int row = fidx >> 5, c4 = fidx & 31;
            f32x4 v = __builtin_nontemporal_load(
                (const f32x4*)(feats + (size_t)(row0 + row) * DD + c4 * 4));
            *(f32x4*)(xs + row * 512 + ((c4 * 16) ^ ((row & 7) << 4))) = v;
        }

        int r = row0 + lj;
        float dgr  = deg[r];
        float invd = 1.0f / fmaxf(dgr, 1.0f);
        float dpown = dgr > 0.5f ? 1.0f : 0.0f;

        // ---- pre fragments: global bf16 NT load, scale by invd ----
        short8 pf[4];
        #pragma unroll
        for (int t = 0; t < 4; ++t) {
            u16x8 pv = __builtin_nontemporal_load(
                (const u16x8*)(pre + (size_t)r * DD + t * 32 + lk * 8));
            unsigned short tmp[8];
            #pragma unroll
            for (int i = 0; i < 8; ++i) tmp[i] = f2bf(bf2f(pv[i]) * invd);
            pf[t] = *(short8*)tmp;
        }
        // ---- X fragments from LDS ----
        short8 xf[4];
        #pragma unroll
        for (int t = 0; t < 4; ++t) {
            f32x4 a = *(const f32x4*)(xs + lj * 512 + ((t * 128 + lk * 32)      ^ xorv));
            f32x4 b = *(const f32x4*)(xs + lj * 512 + ((t * 128 + lk * 32 + 16) ^ xorv));
            unsigned short tmp[8];
            #pragma unroll
            for (int i = 0; i < 4; ++i) { tmp[i] = f2bf(a[i]); tmp[4 + i] = f2bf(b[i]); }
            xf[t] = *(short8*)tmp;
        }

        f32x4 acc[8];
        #pragma unroll
        for (int ct = 0; ct < 8; ++ct) { f32x4 z = {0.f,0.f,0.f,0.f}; acc[ct] = z; }

        #pragma unroll
        for (int t = 0; t < 4; ++t) {
            int a0 = (ldb + t * 64) ^ xorv;
            #pragma unroll
            for (int ct = 0; ct < 8; ++ct) {
                short8 ws = *(const short8*)(wb + ct * 4096 + a0);
                short8 we = *(const short8*)(wb + 32768 + ct * 4096 + a0);
                acc[ct] = __builtin_amdgcn_mfma_f32_16x16x32_bf16(xf[t], ws, acc[ct], 0, 0, 0);
                acc[ct] = __builtin_amdgcn_mfma_f32_16x16x32_bf16(pf[t], we, acc[ct], 0, 0, 0);
            }
        }

        // ---- epilogue; D layout: col = ct*16+lj, row-in-tile = lk*4+q ----
        // Each lane overwrites exactly the residual slot it consumed -> in-place.
        #pragma unroll
        for (int q = 0; q < 4; ++q) {
            int rrl = lk * 4 + q;
            float degpos = __shfl(dpown, rrl, 64);   // lanes 0..15 hold rows 0..15
            float val[8];
            float s = 0.f, s2 = 0.f;
            #pragma unroll
            for (int ct = 0; ct < 8; ++ct) {
                float v = acc[ct][q] + bs[ct] + degpos * bem[ct];
                val[ct] = v; s += v; s2 += v * v;
            }
            #pragma unroll
            for (int m = 1; m < 16; m <<= 1) {
                s  += __shfl_xor(s,  m, 64);
                s2 += __shfl_xor(s2, m, 64);
            }
            float mu   = s * (1.0f / 128.0f);
            float var  = s2 * (1.0f / 128.0f) - mu * mu;
            float rstd = rsqrtf(var + 1e-5f);
            #pragma unroll
            for (int ct = 0; ct < 8; ++ct) {
                int col = ct * 16 + lj;
                int a   = rrl * 512 + ((col * 4) ^ ((rrl & 7) << 4));
                float fres = *(const float*)(xs + a);
                float ln = (val[ct] - mu) * rstd * lw[ct] + lb[ct];
                float x = ln + fres;
                float selu = x > 0.f ? 1.0507009873554805f * x
                                     : 1.0507009873554805f * 1.6732632423543772f * (expf(x) - 1.0f);
                float o = ((fmask >> ct) & 1) ? selu : fres;
                *(float*)(xs + a) = o;
            }
        }

        // ---- coalesced full-line NT stores: 8 x 1KB per wave ----
        #pragma unroll
        for (int j = 0; j < 8; ++j) {
            int fidx = j * 64 + lane;
            int row = fidx >> 5, c4 = fidx & 31;
            f32x4 v = *(const f32x4*)(xs + row * 512 + ((c4 * 16) ^ ((row & 7) << 4)));
            __builtin_nontemporal_store(v, (f32x4*)(out + (size_t)(row0 + row) * DD + c4 * 4));
        }
    }
}

extern "C" void kernel_launch(void* const* d_in, const int* in_sizes, int n_in,
                              void* d_out, int out_size, void* d_ws, size_t ws_size,
                              hipStream_t stream)
{
    const float* feats_A = (const float*)d_in[0];
    const float* feats_B = (const float*)d_in[1];
    const float* W_p2c   = (const float*)d_in[2];
    const float* b_p2c   = (const float*)d_in[3];
    const float* W_c2p   = (const float*)d_in[4];
    const float* b_c2p   = (const float*)d_in[5];
    const float* Wself_A = (const float*)d_in[6];
    const float* bself_A = (const float*)d_in[7];
    const float* lnw_A   = (const float*)d_in[8];
    const float* lnb_A   = (const float*)d_in[9];
    const float* Wself_B = (const float*)d_in[10];
    const float* bself_B = (const float*)d_in[11];
    const float* lnw_B   = (const float*)d_in[12];
    const float* lnb_B   = (const float*)d_in[13];
    const float* u_p2c   = (const float*)d_in[14];
    const float* u_c2p   = (const float*)d_in[15];
    const float* u_featA = (const float*)d_in[16];
    const float* u_featB = (const float*)d_in[17];
    const int* src_p2c = (const int*)d_in[18];
    const int* dst_p2c = (const int*)d_in[19];
    const int* src_c2p = (const int*)d_in[20];
    const int* dst_c2p = (const int*)d_in[21];

    const int N_A = in_sizes[0] / DD;   // 200000
    const int N_B = in_sizes[1] / DD;   // 400000
    const int E1  = in_sizes[14];       // 800000
    const int E2  = in_sizes[15];       // 800000

    float* outA = (float*)d_out;
    float* outB = outA + (size_t)N_A * DD;

    // ws layout: pre_B (bf16), pre_A (bf16), deg_A (f32), deg_B (f32)
    const size_t preB_bytes = (size_t)N_B * DD * 2;   // 102.4MB
    const size_t preA_bytes = (size_t)N_A * DD * 2;   // 51.2MB
    const size_t need = preB_bytes + preA_bytes + (size_t)(N_A + N_B) * 4; // ~156MB
    if (ws_size < need) return;

    unsigned int*   preB_w = (unsigned int*)d_ws;
    unsigned int*   preA_w = (unsigned int*)((char*)d_ws + preB_bytes);
    float*          deg_A  = (float*)((char*)d_ws + preB_bytes + preA_bytes);
    float*          deg_B  = deg_A + N_A;
    const unsigned short* preB_h = (const unsigned short*)preB_w;
    const unsigned short* preA_h = (const unsigned short*)preA_w;

    (void)hipMemsetAsync(d_ws, 0, need, stream);

    dim3 sblk(256), sgrd(2048);
    // PARENT_TO_CHILD: A -> B
    scatter_kernel<<<sgrd, sblk, 0, stream>>>(feats_A, src_p2c, dst_p2c, u_p2c, preB_w, deg_B, E1);
    // CHILD_TO_PARENT: B -> A
    scatter_kernel<<<sgrd, sblk, 0, stream>>>(feats_B, src_c2p, dst_c2p, u_c2p, preA_w, deg_A, E2);

    dim3 tblk(512), tgrd(1024);
    table_kernel<<<tgrd, tblk, 0, stream>>>(feats_A, preA_h, deg_A,
                                            Wself_A, bself_A, W_c2p, b_c2p,
                                            lnw_A, lnb_A, u_featA, outA, N_A);
    table_kernel<<<tgrd, tblk, 0, stream>>>(feats_B, preB_h, deg_B,
                                            Wself_B, bself_B, W_p2c, b_p2c,
                                            lnw_B, lnb_B, u_featB, outB, N_B);
}

// Round 8
// 899.869 us; speedup vs baseline: 1.1566x; 1.1566x over previous
//
#include <hip/hip_runtime.h>
#include <hip/hip_bf16.h>

#define DD 128

typedef __attribute__((ext_vector_type(8))) short short8;
typedef __attribute__((ext_vector_type(8))) unsigned short u16x8;
typedef __attribute__((ext_vector_type(4))) float f32x4;

__device__ __forceinline__ unsigned short f2bf(float f) {
    union { unsigned int u; float f; } c; c.f = f;
    unsigned int u = c.u;
    unsigned int r = (u + 0x7FFFu + ((u >> 16) & 1u)) >> 16;
    return (unsigned short)r;
}
__device__ __forceinline__ float bf2f(unsigned short h) {
    union { unsigned int u; float f; } c; c.u = ((unsigned int)h) << 16; return c.f;
}

// -------- scatter: pre[dst] += bf16(feats[src]) via pk_add_bf16, deg[dst] += 1 --------
__global__ void scatter_kernel(const float* __restrict__ feats,
                               const int* __restrict__ src,
                               const int* __restrict__ dst,
                               const float* __restrict__ u,
                               unsigned int* __restrict__ pre,   // bf16x2 words, 64 per row
                               float* __restrict__ deg,
                               int E)
{
    int gtid = blockIdx.x * blockDim.x + threadIdx.x;
    int lane = gtid & 63;
    int wave = gtid >> 6;
    int nw   = (gridDim.x * blockDim.x) >> 6;
    for (int e = wave; e < E; e += nw) {
        if (u[e] < 0.5f) {
            int s = src[e], d = dst[e];
            float2 x = *(const float2*)(feats + (size_t)s * DD + 2 * lane);
            unsigned int* p = pre + (size_t)d * 64 + lane;
#if defined(__HIP_DEVICE_COMPILE__)
            typedef short sv2 __attribute__((ext_vector_type(2)));
            sv2 v; v[0] = (short)f2bf(x.x); v[1] = (short)f2bf(x.y);
            __builtin_amdgcn_global_atomic_fadd_v2bf16((__attribute__((address_space(1))) sv2*)p, v);
#else
            (void)p; (void)x;
#endif
            if (lane == 0) unsafeAtomicAdd(deg + d, 1.0f);
        }
    }
}

// -------- barrier-free table update, fragment-direct loads, 2-deep pipeline --------
// comb = X@Wself^T + bself + fmask*((pre/deg)@Wedge^T + (deg>0)*bedge)
// LN -> +residual -> SELU -> column-mask select
// Weights in LDS (bf16, XOR-swizzled). X-fragment loaded global->reg directly;
// its bf16 pack doubles as the residual copy staged in a per-wave bf16 LDS tile.
// Two xs buffers per wave + unroll 2 => next tile's global loads overlap
// current tile's MFMA/epilogue (intra-wave pipeline, no barriers).
__global__ __launch_bounds__(512, 2)
void table_kernel(const float* __restrict__ feats,
                  const unsigned short* __restrict__ pre,   // bf16
                  const float* __restrict__ deg,
                  const float* __restrict__ Wself,
                  const float* __restrict__ bself,
                  const float* __restrict__ Wedge,
                  const float* __restrict__ bedge,
                  const float* __restrict__ lnw,
                  const float* __restrict__ lnb,
                  const float* __restrict__ ufeat,
                  float* __restrict__ out,
                  int N)
{
    __shared__ __align__(16) unsigned short wlds[2 * 16384];  // 64KB weights (bf16, swizzled)
    __shared__ __align__(16) char xsall[8 * 8192];            // 64KB: 8 waves x 2 x 4KB bf16 tiles

    const int tid = threadIdx.x;

    // ---- one-time weight staging: f32 -> bf16, XOR-swizzled (addr ^= (j&7)<<4) ----
    {
        int j  = tid >> 2;        // W row (output col) 0..127
        int kq = tid & 3;         // k quarter
        float fm = ufeat[j] < 0.3f ? 1.0f : 0.0f;
        const float* wsrow = Wself + j * DD + kq * 32;
        const float* werow = Wedge + j * DD + kq * 32;
        char* lbs = (char*)wlds;
        #pragma unroll
        for (int c = 0; c < 4; ++c) {
            unsigned short tS[8], tE[8];
            #pragma unroll
            for (int i = 0; i < 8; ++i) {
                tS[i] = f2bf(wsrow[c * 8 + i]);
                tE[i] = f2bf(werow[c * 8 + i] * fm);
            }
            int addr = (j * 256 + kq * 64 + c * 16) ^ ((j & 7) << 4);
            *(short8*)(lbs + addr)         = *(short8*)tS;
            *(short8*)(lbs + 32768 + addr) = *(short8*)tE;
        }
    }
    __syncthreads();   // only barrier in the kernel

    const int wave = tid >> 6;
    const int lane = tid & 63;
    const int lj = lane & 15;
    const int lk = lane >> 4;

    // per-lane column constants (col = ct*16 + lj)
    float bs[8], bem[8], lw[8], lb[8];
    unsigned fmask = 0;
    #pragma unroll
    for (int ct = 0; ct < 8; ++ct) {
        int col = ct * 16 + lj;
        bool fm = ufeat[col] < 0.3f;
        bs[ct]  = bself[col];
        bem[ct] = fm ? bedge[col] : 0.0f;
        lw[ct]  = lnw[col];
        lb[ct]  = lnb[col];
        fmask |= (fm ? 1u : 0u) << ct;
    }

    char* xs0 = xsall + wave * 8192;
    const char* wb = (const char*)wlds;
    const int ldb  = lj * 256 + lk * 16;
    const int xorv = (lj & 7) << 4;

    const int ntiles = N >> 4;
    int itc = 0;
    #pragma unroll 2
    for (int tile = blockIdx.x * 8 + wave; tile < ntiles; tile += gridDim.x * 8) {
        char* xsb = xs0 + ((itc & 1) << 12);
        ++itc;
        int row0 = tile << 4;
        int r = row0 + lj;

        // ---- issue all global loads for this tile up front ----
        const float* xrow = feats + (size_t)r * DD + lk * 8;
        f32x4 xr[8];
        #pragma unroll
        for (int t = 0; t < 4; ++t) {
            xr[2 * t]     = __builtin_nontemporal_load((const f32x4*)(xrow + t * 32));
            xr[2 * t + 1] = __builtin_nontemporal_load((const f32x4*)(xrow + t * 32 + 4));
        }
        u16x8 pv[4];
        #pragma unroll
        for (int t = 0; t < 4; ++t)
            pv[t] = __builtin_nontemporal_load(
                (const u16x8*)(pre + (size_t)r * DD + t * 32 + lk * 8));
        float dgr  = deg[r];
        float invd = 1.0f / fmaxf(dgr, 1.0f);
        float dpown = dgr > 0.5f ? 1.0f : 0.0f;

        // ---- pack fragments; xf doubles as residual -> stage bf16 tile to LDS ----
        short8 xf[4], pf[4];
        #pragma unroll
        for (int t = 0; t < 4; ++t) {
            unsigned short tx[8], tp[8];
            #pragma unroll
            for (int i = 0; i < 4; ++i) {
                tx[i]     = f2bf(xr[2 * t][i]);
                tx[4 + i] = f2bf(xr[2 * t + 1][i]);
            }
            #pragma unroll
            for (int i = 0; i < 8; ++i) tp[i] = f2bf(bf2f(pv[t][i]) * invd);
            xf[t] = *(short8*)tx;
            pf[t] = *(short8*)tp;
            *(short8*)(xsb + ((lj * 256 + t * 64 + lk * 16) ^ xorv)) = xf[t];
        }

        f32x4 acc[8];
        #pragma unroll
        for (int ct = 0; ct < 8; ++ct) { f32x4 z = {0.f,0.f,0.f,0.f}; acc[ct] = z; }

        #pragma unroll
        for (int t = 0; t < 4; ++t) {
            int a0 = (ldb + t * 64) ^ xorv;
            #pragma unroll
            for (int ct = 0; ct < 8; ++ct) {
                short8 ws = *(const short8*)(wb + ct * 4096 + a0);
                short8 we = *(const short8*)(wb + 32768 + ct * 4096 + a0);
                acc[ct] = __builtin_amdgcn_mfma_f32_16x16x32_bf16(xf[t], ws, acc[ct], 0, 0, 0);
                acc[ct] = __builtin_amdgcn_mfma_f32_16x16x32_bf16(pf[t], we, acc[ct], 0, 0, 0);
            }
        }

        // ---- epilogue; D layout: col = ct*16+lj, row-in-tile = lk*4+q ----
        #pragma unroll
        for (int q = 0; q < 4; ++q) {
            int rrl = lk * 4 + q;
            float degpos = __shfl(dpown, rrl, 64);   // lanes 0..15 hold rows 0..15
            float val[8];
            float s = 0.f, s2 = 0.f;
            #pragma unroll
            for (int ct = 0; ct < 8; ++ct) {
                float v = acc[ct][q] + bs[ct] + degpos * bem[ct];
                val[ct] = v; s += v; s2 += v * v;
            }
            #pragma unroll
            for (int m = 1; m < 16; m <<= 1) {
                s  += __shfl_xor(s,  m, 64);
                s2 += __shfl_xor(s2, m, 64);
            }
            float mu   = s * (1.0f / 128.0f);
            float var  = s2 * (1.0f / 128.0f) - mu * mu;
            float rstd = rsqrtf(var + 1e-5f);
            #pragma unroll
            for (int ct = 0; ct < 8; ++ct) {
                int col = ct * 16 + lj;
                int ra  = rrl * 256 + ((col * 2) ^ ((rrl & 7) << 4));
                float fres = bf2f(*(const unsigned short*)(xsb + ra));
                float ln = (val[ct] - mu) * rstd * lw[ct] + lb[ct];
                float x = ln + fres;
                float selu = x > 0.f ? 1.0507009873554805f * x
                                     : 1.0507009873554805f * 1.6732632423543772f * (expf(x) - 1.0f);
                float o = ((fmask >> ct) & 1) ? selu : fres;
                *(unsigned short*)(xsb + ra) = f2bf(o);   // in-place 2B
            }
        }

        // ---- coalesced readback + plain vector stores (L2 write-combining) ----
        #pragma unroll
        for (int j = 0; j < 4; ++j) {
            int row = j * 4 + lk;
            int ba  = row * 256 + ((lj * 16) ^ ((row & 7) << 4));
            u16x8 ov = *(const u16x8*)(xsb + ba);
            f32x4 o0, o1;
            #pragma unroll
            for (int i = 0; i < 4; ++i) { o0[i] = bf2f(ov[i]); o1[i] = bf2f(ov[4 + i]); }
            float* op = out + (size_t)(row0 + row) * DD + lj * 8;
            *(f32x4*)op       = o0;
            *(f32x4*)(op + 4) = o1;
        }
    }
}

extern "C" void kernel_launch(void* const* d_in, const int* in_sizes, int n_in,
                              void* d_out, int out_size, void* d_ws, size_t ws_size,
                              hipStream_t stream)
{
    const float* feats_A = (const float*)d_in[0];
    const float* feats_B = (const float*)d_in[1];
    const float* W_p2c   = (const float*)d_in[2];
    const float* b_p2c   = (const float*)d_in[3];
    const float* W_c2p   = (const float*)d_in[4];
    const float* b_c2p   = (const float*)d_in[5];
    const float* Wself_A = (const float*)d_in[6];
    const float* bself_A = (const float*)d_in[7];
    const float* lnw_A   = (const float*)d_in[8];
    const float* lnb_A   = (const float*)d_in[9];
    const float* Wself_B = (const float*)d_in[10];
    const float* bself_B = (const float*)d_in[11];
    const float* lnw_B   = (const float*)d_in[12];
    const float* lnb_B   = (const float*)d_in[13];
    const float* u_p2c   = (const float*)d_in[14];
    const float* u_c2p   = (const float*)d_in[15];
    const float* u_featA = (const float*)d_in[16];
    const float* u_featB = (const float*)d_in[17];
    const int* src_p2c = (const int*)d_in[18];
    const int* dst_p2c = (const int*)d_in[19];
    const int* src_c2p = (const int*)d_in[20];
    const int* dst_c2p = (const int*)d_in[21];

    const int N_A = in_sizes[0] / DD;   // 200000
    const int N_B = in_sizes[1] / DD;   // 400000
    const int E1  = in_sizes[14];       // 800000
    const int E2  = in_sizes[15];       // 800000

    float* outA = (float*)d_out;
    float* outB = outA + (size_t)N_A * DD;

    // ws layout: pre_B (bf16), pre_A (bf16), deg_A (f32), deg_B (f32)
    const size_t preB_bytes = (size_t)N_B * DD * 2;   // 102.4MB
    const size_t preA_bytes = (size_t)N_A * DD * 2;   // 51.2MB
    const size_t need = preB_bytes + preA_bytes + (size_t)(N_A + N_B) * 4; // ~156MB
    if (ws_size < need) return;

    unsigned int*   preB_w = (unsigned int*)d_ws;
    unsigned int*   preA_w = (unsigned int*)((char*)d_ws + preB_bytes);
    float*          deg_A  = (float*)((char*)d_ws + preB_bytes + preA_bytes);
    float*          deg_B  = deg_A + N_A;
    const unsigned short* preB_h = (const unsigned short*)preB_w;
    const unsigned short* preA_h = (const unsigned short*)preA_w;

    (void)hipMemsetAsync(d_ws, 0, need, stream);

    dim3 sblk(256), sgrd(2048);
    // PARENT_TO_CHILD: A -> B
    scatter_kernel<<<sgrd, sblk, 0, stream>>>(feats_A, src_p2c, dst_p2c, u_p2c, preB_w, deg_B, E1);
    // CHILD_TO_PARENT: B -> A
    scatter_kernel<<<sgrd, sblk, 0, stream>>>(feats_B, src_c2p, dst_c2p, u_c2p, preA_w, deg_A, E2);

    dim3 tblk(512), tgrd(256);   // 1 block per CU: weights staged once per CU
    table_kernel<<<tgrd, tblk, 0, stream>>>(feats_A, preA_h, deg_A,
                                            Wself_A, bself_A, W_c2p, b_c2p,
                                            lnw_A, lnb_A, u_featA, outA, N_A);
    table_kernel<<<tgrd, tblk, 0, stream>>>(feats_B, preB_h, deg_B,
                                            Wself_B, bself_B, W_p2c, b_p2c,
                                            lnw_B, lnb_B, u_featB, outB, N_B);
}